// Round 19
// baseline (115.880 us; speedup 1.0000x reference)
//
#include <hip/hip_runtime.h>

#define DM 1024
#define NHEAD 16
#define DK 64
#define QLD 3072   // fused QKV row stride

typedef short bf16x8 __attribute__((ext_vector_type(8)));
typedef float f32x4 __attribute__((ext_vector_type(4)));

__device__ __forceinline__ unsigned short f2bf(float f) {
  union { float f; unsigned u; } v; v.f = f;
  return (unsigned short)((v.u + 0x7fffu + ((v.u >> 16) & 1u)) >> 16);
}
__device__ __forceinline__ float bf2f(unsigned short h) {
  union { unsigned u; float f; } v; v.u = ((unsigned)h) << 16; return v.f;
}
__device__ __forceinline__ float fexp2(float x) {   // bare v_exp_f32: args bounded, no fixup needed
  float r; asm("v_exp_f32 %0, %1" : "=v"(r) : "v"(x)); return r;
}

__device__ __forceinline__ void gld16(const void* g, void* l) {
  __builtin_amdgcn_global_load_lds((const __attribute__((address_space(1))) void*)g,
                                   (__attribute__((address_space(3))) void*)l, 16, 0, 0);
}

__device__ __forceinline__ uint4 pack8(float4 a, float4 b, float sc) {
  uint4 r;
  r.x = (unsigned)f2bf(a.x * sc) | ((unsigned)f2bf(a.y * sc) << 16);
  r.y = (unsigned)f2bf(a.z * sc) | ((unsigned)f2bf(a.w * sc) << 16);
  r.z = (unsigned)f2bf(b.x * sc) | ((unsigned)f2bf(b.y * sc) << 16);
  r.w = (unsigned)f2bf(b.z * sc) | ((unsigned)f2bf(b.w * sc) << 16);
  return r;
}

// kappa: key = K(slot) within each 64-tile; bijective. Matches swapped-QK register layout.
__device__ __forceinline__ int kappa(int p) {
  return (p & 32) + (((p & 7) >> 2) << 4) + (((p >> 3) & 3) << 2) + (p & 3);
}

// ---------------- fused prep: x conv + 4 weight convs (8 elems/thread) + bias cat + tw ----------------
__global__ void k_prep(const float* __restrict__ x, const float* __restrict__ Wq,
                       const float* __restrict__ Wk, const float* __restrict__ Wv,
                       const float* __restrict__ Wo, const float* __restrict__ bq,
                       const float* __restrict__ bk, const float* __restrict__ bv,
                       const float* __restrict__ coords,
                       unsigned short* __restrict__ xb, unsigned short* __restrict__ Wcat,
                       unsigned short* __restrict__ Wob, float* __restrict__ bcat,
                       float* __restrict__ tw, unsigned short* __restrict__ twb,
                       int M, int S, float QS) {
  const int nx8 = M * DM / 8;      // x 8-float chunks
  const int nw8 = DM * DM / 8;     // per-weight 8-float chunks
  const int total = nx8 + 4 * nw8;
  int gid = blockIdx.x * 256 + threadIdx.x;

  auto conv8 = [&](const float* src, unsigned short* dst, int idx, float sc) {
    float4 a = *(const float4*)(src + idx * 8);
    float4 b = *(const float4*)(src + idx * 8 + 4);
    *(uint4*)(dst + idx * 8) = pack8(a, b, sc);
  };

  if (gid < nx8) { conv8(x, xb, gid, 1.0f); return; }
  if (gid < nx8 + nw8) { conv8(Wq, Wcat, gid - nx8, QS); return; }
  if (gid < nx8 + 2 * nw8) { conv8(Wk, Wcat + DM * DM, gid - nx8 - nw8, 1.0f); return; }
  if (gid < nx8 + 3 * nw8) { conv8(Wv, Wcat + 2 * DM * DM, gid - nx8 - 2 * nw8, 1.0f); return; }
  if (gid < total) { conv8(Wo, Wob, gid - nx8 - 3 * nw8, 1.0f); return; }

  int r = gid - total;
  if (r < 3 * DM) {
    float v = (r < DM) ? bq[r] * QS : (r < 2 * DM ? bk[r - DM] : bv[r - 2 * DM]);
    bcat[r] = v;
    return;
  }
  r -= 3 * DM;
  if (r < S) {
    auto twval = [&](int k) {
      float a = (k > 0)     ? fabsf(coords[k] - coords[k - 1]) : 0.f;
      float b = (k < S - 1) ? fabsf(coords[k + 1] - coords[k]) : 0.f;
      return 0.5f * (a + b);
    };
    tw[r] = twval(r);
    int key = (r & ~63) + kappa(r & 63);
    twb[r] = f2bf(twval(key));
  }
}

// ---------------- GEMM: C[M,N] = A[M,K] * B[N,K]^T + bias (bf16 out) ----------------
// T2 XOR-swizzled LDS; C stored via LDS restage for coalescing; static dbuf indices.
// VFUSE: blocks covering the V feature range write transposed/tw-scaled/kappa-permuted
// Vt tiles directly (and skip the C store) — replaces the k_transpose kernel.
#define BM 128
#define BN 128
#define BKK 64

template<int VFUSE>
__global__ __launch_bounds__(256)
void gemm_bt(const unsigned short* __restrict__ A, const unsigned short* __restrict__ B,
             const float* __restrict__ bias, void* __restrict__ C,
             int M, int N, int K, int ldc,
             const float* __restrict__ twp, unsigned short* __restrict__ Vt, int S) {
  __shared__ __align__(16) unsigned short smem[4][BM * BKK];   // [0..1]=A dbuf, [2..3]=B dbuf
  const int tid = threadIdx.x;
  const int lane = tid & 63;
  const int wid = tid >> 6;
  const int rr = lane & 15, g = lane >> 4;
  const int nbn = N / BN;
  const int cpx = gridDim.x >> 3;
  const int bid = ((gridDim.x & 7) == 0) ? (blockIdx.x & 7) * cpx + (blockIdx.x >> 3)
                                         : blockIdx.x;
  const int bm = bid / nbn, bn = bid % nbn;
  const int wr = wid >> 1, wc = wid & 1;
  const int nkt = K / BKK;   // 16 (even)

  const unsigned short* Abase = A + (size_t)bm * BM * K;
  const unsigned short* Bbase = B + (size_t)bn * BN * K;

  auto stage = [&](int buf, int kt) {
#pragma unroll
    for (int j = 0; j < 4; ++j) {
      int o = j * 256 + tid;
      int row = o >> 3;
      int cb = ((o & 7) * 16) ^ ((row & 7) << 4);   // inverse-swizzled source byte col
      gld16((const char*)(Abase + (size_t)row * K + kt * BKK) + cb, &smem[buf][o * 8]);
      gld16((const char*)(Bbase + (size_t)row * K + kt * BKK) + cb, &smem[2 + buf][o * 8]);
    }
  };

  f32x4 acc[4][4] = {};
  const int sw = (rr & 7) << 4;

  auto giter = [&](int buf, int kt) {
    __syncthreads();
    if (kt + 1 < nkt) stage(buf ^ 1, kt + 1);
    const char* a0 = (const char*)&smem[buf][0];
    const char* b0 = (const char*)&smem[2 + buf][0];
#pragma unroll
    for (int kk = 0; kk < 2; ++kk) {
      const int co = (kk * 64 + g * 16);
      bf16x8 af[4], bfr[4];
#pragma unroll
      for (int m = 0; m < 4; ++m)
        af[m] = *(const bf16x8*)(a0 + (wr * 64 + m * 16 + rr) * 128 + (co ^ sw));
#pragma unroll
      for (int n = 0; n < 4; ++n)
        bfr[n] = *(const bf16x8*)(b0 + (wc * 64 + n * 16 + rr) * 128 + (co ^ sw));
      __builtin_amdgcn_s_setprio(1);
#pragma unroll
      for (int m = 0; m < 4; ++m)
#pragma unroll
        for (int n = 0; n < 4; ++n)
          acc[m][n] = __builtin_amdgcn_mfma_f32_16x16x32_bf16(af[m], bfr[n], acc[m][n], 0, 0, 0);
      __builtin_amdgcn_s_setprio(0);
    }
  };

  stage(0, 0);
  for (int kt2 = 0; kt2 < nkt; kt2 += 2) {
    giter(0, kt2);
    giter(1, kt2 + 1);
  }

  const int ccol0 = bn * BN + wc * 64;
  // restage through LDS (row pad 136 shorts)
  unsigned short* L = &smem[0][0];   // 128*136 = 17408 shorts <= 32768
  __syncthreads();                   // all fragment reads of smem done
#pragma unroll
  for (int n = 0; n < 4; ++n) {
    const float bn_ = bias ? bias[ccol0 + n * 16 + rr] : 0.f;
#pragma unroll
    for (int m = 0; m < 4; ++m)
#pragma unroll
      for (int r = 0; r < 4; ++r)
        L[(wr * 64 + m * 16 + g * 4 + r) * 136 + wc * 64 + n * 16 + rr] =
            f2bf(acc[m][n][r] + bn_);
  }
  __syncthreads();
  if (VFUSE && bn >= (2 * DM) / BN) {
    // ---- fused V-transpose epilogue: Vt[bh][d][s] with tw prescale + kappa permute ----
    const int tilesPerB = S / BM;
    const int bb = bm / tilesPerB;
    const int s0 = (bm % tilesPerB) * BM;
    const int vcol0 = bn * BN - 2 * DM;        // first V feature col of this tile
    const int hh = tid >> 7;                   // head-half within tile (0/1)
    const int dd = (tid >> 1) & 63;            // d within head
    const int stl = tid & 1;                   // which 64-s subtile
    const int head = (vcol0 >> 6) + hh;
    const int lcol = hh * 64 + dd;
    unsigned short* vdst = Vt + ((size_t)(bb * NHEAD + head) * DK + dd) * S + s0 + stl * 64;
    const float* twg = twp + s0 + stl * 64;
    unsigned short tmp[8];
#pragma unroll
    for (int j8 = 0; j8 < 8; ++j8) {
#pragma unroll
      for (int j = 0; j < 8; ++j) {
        const int kl = kappa(j8 * 8 + j);
        tmp[j] = f2bf(bf2f(L[(stl * 64 + kl) * 136 + lcol]) * twg[kl]);
      }
      *(uint4*)&vdst[j8 * 8] = *(const uint4*)&tmp[0];
    }
  } else {
    unsigned short* Cb = (unsigned short*)C + (size_t)(bm * BM) * ldc + bn * BN;
#pragma unroll
    for (int i = 0; i < 8; ++i) {
      int o = i * 256 + tid;
      int row = o >> 4;
      int cc = (o & 15) * 8;
      uint4 v = *(const uint4*)&L[row * 136 + cc];
      *(uint4*)&Cb[(size_t)row * ldc + cc] = v;
    }
  }
}

// ---------------- Wo GEMM: C[M,N] f32 = A[M,K]*B[N,K]^T + bias; BM=64 x BN=128 tile ----------------
// 512 blocks (2/CU). 2x2 wave grid, per-wave 32x64. f32 LDS-restaged coalesced store.
#define WBM 64
__global__ __launch_bounds__(256)
void gemm_wo(const unsigned short* __restrict__ A, const unsigned short* __restrict__ B,
             const float* __restrict__ bias, float* __restrict__ C,
             int M, int N, int K, int ldc) {
  __shared__ __align__(16) unsigned short smem[6][WBM * BKK];  // [0..1]=A dbuf(16KB), [2..5]=B dbuf(32KB)
  const int tid = threadIdx.x;
  const int lane = tid & 63;
  const int wid = tid >> 6;
  const int rr = lane & 15, g = lane >> 4;
  const int nbn = N / BN;                       // 8
  const int cpx = gridDim.x >> 3;
  const int bid = (blockIdx.x & 7) * cpx + (blockIdx.x >> 3);   // grid 512 % 8 == 0
  const int bm = bid / nbn, bn = bid % nbn;
  const int wr = wid >> 1, wc = wid & 1;
  const int nkt = K / BKK;   // 16 (even)

  const unsigned short* Abase = A + (size_t)bm * WBM * K;
  const unsigned short* Bbase = B + (size_t)bn * BN * K;

  auto stage = [&](int buf, int kt) {
    {   // A: 64 rows x 128B = 512 chunks -> 2/thread
#pragma unroll
      for (int j = 0; j < 2; ++j) {
        int o = j * 256 + tid;
        int row = o >> 3;
        int cb = ((o & 7) * 16) ^ ((row & 7) << 4);
        gld16((const char*)(Abase + (size_t)row * K + kt * BKK) + cb, &smem[buf][o * 8]);
      }
    }
    {   // B: 128 rows x 128B = 1024 chunks -> 4/thread
#pragma unroll
      for (int j = 0; j < 4; ++j) {
        int o = j * 256 + tid;
        int row = o >> 3;
        int cb = ((o & 7) * 16) ^ ((row & 7) << 4);
        gld16((const char*)(Bbase + (size_t)row * K + kt * BKK) + cb, &smem[2 + buf * 2][o * 8]);
      }
    }
  };

  f32x4 acc[2][4] = {};
  const int sw = (rr & 7) << 4;

  auto giter = [&](int buf, int kt) {
    __syncthreads();
    if (kt + 1 < nkt) stage(buf ^ 1, kt + 1);
    const char* a0 = (const char*)&smem[buf][0];
    const char* b0 = (const char*)&smem[2 + buf * 2][0];
#pragma unroll
    for (int kk = 0; kk < 2; ++kk) {
      const int co = (kk * 64 + g * 16);
      bf16x8 af[2], bfr[4];
#pragma unroll
      for (int m = 0; m < 2; ++m)
        af[m] = *(const bf16x8*)(a0 + (wr * 32 + m * 16 + rr) * 128 + (co ^ sw));
#pragma unroll
      for (int n = 0; n < 4; ++n)
        bfr[n] = *(const bf16x8*)(b0 + (wc * 64 + n * 16 + rr) * 128 + (co ^ sw));
      __builtin_amdgcn_s_setprio(1);
#pragma unroll
      for (int m = 0; m < 2; ++m)
#pragma unroll
        for (int n = 0; n < 4; ++n)
          acc[m][n] = __builtin_amdgcn_mfma_f32_16x16x32_bf16(af[m], bfr[n], acc[m][n], 0, 0, 0);
      __builtin_amdgcn_s_setprio(0);
    }
  };

  stage(0, 0);
  for (int kt2 = 0; kt2 < nkt; kt2 += 2) {
    giter(0, kt2);
    giter(1, kt2 + 1);
  }

  // f32 restage: 64 rows x 132 f32 (pad 4 -> banks shift 4/row), 33.8KB within 48KB smem
  float* Lf = (float*)&smem[0][0];
  __syncthreads();
#pragma unroll
  for (int n = 0; n < 4; ++n) {
    const float bn_ = bias[bn * BN + wc * 64 + n * 16 + rr];
#pragma unroll
    for (int m = 0; m < 2; ++m)
#pragma unroll
      for (int r = 0; r < 4; ++r)
        Lf[(wr * 32 + m * 16 + g * 4 + r) * 132 + wc * 64 + n * 16 + rr] =
            acc[m][n][r] + bn_;
  }
  __syncthreads();
  float* Cb = C + (size_t)(bm * WBM) * ldc + bn * BN;
#pragma unroll
  for (int i = 0; i < 8; ++i) {
    int o = i * 256 + tid;         // 2048 uint4 chunks: 64 rows x 32 chunks
    int row = o >> 5;
    int cc = (o & 31) * 4;
    float4 v = *(const float4*)&Lf[row * 132 + cc];
    *(float4*)&Cb[(size_t)row * ldc + cc] = v;
  }
}

// ---------------- attention: swapped QK^T, P in registers, KVBLK=128 ----------------
// 4 waves x 32 q-rows = 128 q-rows per block; 128-key staged tiles, two 64-key halves.
// Static dbuf indices; V/tw frags for BOTH halves hoisted to kt-top; coalesced epilogue.
__global__ __launch_bounds__(256)
void k_attn(const unsigned short* __restrict__ QKV, const unsigned short* __restrict__ Vt,
            const unsigned short* __restrict__ twb, unsigned short* __restrict__ O, int S) {
  __shared__ __align__(16) unsigned short sK[2][128 * 64];      // 128 keys x 64 d
  __shared__ __align__(16) unsigned short sV[2][2][64 * 64];    // [buf][half][64 d][64 slots]
  const int tid = threadIdx.x, lane = tid & 63, wid = tid >> 6;
  const int rr = lane & 15, g = lane >> 4;
  const int nqt = S / 128;
  const int cpx = gridDim.x >> 3;
  const int swz = (blockIdx.x & 7) * cpx + (blockIdx.x >> 3);
  const int qt = swz % nqt;
  const int bh = swz / nqt;
  const int h = bh & (NHEAD - 1), b = bh / NHEAD;

  const unsigned short* Qbase = QKV + ((size_t)b * S + qt * 128 + wid * 32) * QLD + h * DK;
  const unsigned short* Kbase = QKV + (size_t)b * S * QLD + DM + h * DK;
  const unsigned short* Vbase = Vt + (size_t)bh * DK * S;

  bf16x8 aq[2][2];
#pragma unroll
  for (int qm = 0; qm < 2; ++qm) {
    aq[qm][0] = *(const bf16x8*)&Qbase[(size_t)(qm * 16 + rr) * QLD + g * 8];
    aq[qm][1] = *(const bf16x8*)&Qbase[(size_t)(qm * 16 + rr) * QLD + 32 + g * 8];
  }

  f32x4 acc[2][5] = {};
  const f32x4 z0 = {};
  const int nkt = S / 128;   // 16 (even)
  const int swr = (rr & 7) << 4;   // row&7 == rr&7 for all frag rows

  auto stage = [&](int buf, int kt) {
    // K: 128 rows x 128B, 1024 chunks
#pragma unroll
    for (int j = 0; j < 4; ++j) {
      int o = j * 256 + tid;
      int row = o >> 3;
      int cb = ((o & 7) * 16) ^ ((row & 7) << 4);
      gld16((const char*)(Kbase + (size_t)(kt * 128 + row) * QLD) + cb, &sK[buf][o * 8]);
    }
    // V: 2 halves x (64 rows x 128B), 1024 chunks; dest stays linear (o*8)
#pragma unroll
    for (int j = 0; j < 4; ++j) {
      int o = j * 256 + tid;
      int half_ = o >> 9;
      int r = o & 511;
      int row = r >> 3;
      int cb = ((r & 7) * 16) ^ ((row & 7) << 4);
      gld16((const char*)(Vbase + (size_t)row * S + kt * 128 + half_ * 64) + cb,
            &sV[buf][0][o * 8]);
    }
  };

  auto iter = [&](int buf, int kt) {
    __syncthreads();
    if (kt + 1 < nkt) stage(buf ^ 1, kt + 1);

    // ---- hoisted: V frags + tw frags for BOTH halves at kt-top ----
    bf16x8 vB[2][2][4];
#pragma unroll
    for (int half = 0; half < 2; ++half)
#pragma unroll
      for (int kk = 0; kk < 2; ++kk)
#pragma unroll
        for (int n = 0; n < 4; ++n) {
          const int vrow = n * 16 + rr;
          const int cb = (kk * 64 + g * 16) ^ ((vrow & 7) << 4);
          vB[half][kk][n] = *(const bf16x8*)((const char*)&sV[buf][half][vrow * 64] + cb);
        }
    bf16x8 twf[2][2];
#pragma unroll
    for (int half = 0; half < 2; ++half)
#pragma unroll
      for (int kk = 0; kk < 2; ++kk)
        twf[half][kk] = *(const bf16x8*)&twb[kt * 128 + half * 64 + kk * 32 + g * 8];

#pragma unroll
    for (int half = 0; half < 2; ++half) {
      // K frags for this half
      bf16x8 kA[4][2];
#pragma unroll
      for (int f = 0; f < 4; ++f) {
        const int row = half * 64 + f * 16 + rr;
        kA[f][0] = *(const bf16x8*)((const char*)&sK[buf][row * 64] + ((g * 16) ^ swr));
        kA[f][1] = *(const bf16x8*)((const char*)&sK[buf][row * 64] + ((64 + g * 16) ^ swr));
      }

      // ---- swapped scores: s[qm][f] = P[key=16f+4g+r][q=qm*16+rr] ----
      f32x4 s[2][4];
      __builtin_amdgcn_s_setprio(1);
#pragma unroll
      for (int f = 0; f < 4; ++f)
#pragma unroll
        for (int qm = 0; qm < 2; ++qm) {
          f32x4 z = __builtin_amdgcn_mfma_f32_16x16x32_bf16(kA[f][0], aq[qm][0], z0, 0, 0, 0);
          s[qm][f] = __builtin_amdgcn_mfma_f32_16x16x32_bf16(kA[f][1], aq[qm][1], z, 0, 0, 0);
        }
      __builtin_amdgcn_s_setprio(0);

      // ---- p = exp2(s) in place (lane-local) ----
#pragma unroll
      for (int qm = 0; qm < 2; ++qm)
#pragma unroll
        for (int f = 0; f < 4; ++f)
#pragma unroll
          for (int r = 0; r < 4; ++r)
            s[qm][f][r] = fexp2(s[qm][f][r]);

      // ---- pack P into A-frags: slot kk*32+g*8+j -> (f=2kk+(j>>2), r=j&3) ----
      bf16x8 pa[2][2];
#pragma unroll
      for (int qm = 0; qm < 2; ++qm)
#pragma unroll
        for (int kk = 0; kk < 2; ++kk) {
          union { bf16x8 v; unsigned u[4]; } pk;
          asm("v_cvt_pk_bf16_f32 %0, %1, %2" : "=v"(pk.u[0]) : "v"(s[qm][2*kk][0]),   "v"(s[qm][2*kk][1]));
          asm("v_cvt_pk_bf16_f32 %0, %1, %2" : "=v"(pk.u[1]) : "v"(s[qm][2*kk][2]),   "v"(s[qm][2*kk][3]));
          asm("v_cvt_pk_bf16_f32 %0, %1, %2" : "=v"(pk.u[2]) : "v"(s[qm][2*kk+1][0]), "v"(s[qm][2*kk+1][1]));
          asm("v_cvt_pk_bf16_f32 %0, %1, %2" : "=v"(pk.u[3]) : "v"(s[qm][2*kk+1][2]), "v"(s[qm][2*kk+1][3]));
          pa[qm][kk] = pk.v;
        }

      // ---- PV + denominator (operands already in registers) ----
      __builtin_amdgcn_s_setprio(1);
#pragma unroll
      for (int kk = 0; kk < 2; ++kk) {
#pragma unroll
        for (int n = 0; n < 4; ++n)
#pragma unroll
          for (int qm = 0; qm < 2; ++qm)
            acc[qm][n] = __builtin_amdgcn_mfma_f32_16x16x32_bf16(pa[qm][kk], vB[half][kk][n], acc[qm][n], 0, 0, 0);
#pragma unroll
        for (int qm = 0; qm < 2; ++qm)
          acc[qm][4] = __builtin_amdgcn_mfma_f32_16x16x32_bf16(pa[qm][kk], twf[half][kk], acc[qm][4], 0, 0, 0);
      }
      __builtin_amdgcn_s_setprio(0);
    }
  };

  stage(0, 0);
  for (int kt2 = 0; kt2 < nkt; kt2 += 2) {
    iter(0, kt2);
    iter(1, kt2 + 1);
  }

  // ---- coalesced epilogue: restage O tile (128 x 64 bf16) in LDS, 16B/lane stores ----
  unsigned short* L = &sK[0][0];   // 128*72 = 9216 shorts <= 16384 (sK region)
  __syncthreads();                 // all waves done reading sK/sV
#pragma unroll
  for (int qm = 0; qm < 2; ++qm)
#pragma unroll
    for (int n = 0; n < 4; ++n)
#pragma unroll
      for (int r = 0; r < 4; ++r)
        L[(wid * 32 + qm * 16 + g * 4 + r) * 72 + n * 16 + rr] =
            f2bf(acc[qm][n][r] / acc[qm][4][r]);
  __syncthreads();
  unsigned short* Ob = O + ((size_t)b * S + qt * 128) * DM + h * DK;
#pragma unroll
  for (int i = 0; i < 4; ++i) {
    int o = i * 256 + tid;         // 1024 chunks: 128 rows x 8 chunks of 16B
    int row = o >> 3;
    int c = (o & 7) * 8;
    uint4 v = *(const uint4*)&L[row * 72 + c];
    *(uint4*)&Ob[(size_t)row * DM + c] = v;
  }
}

// ---------------- launch ----------------
extern "C" void kernel_launch(void* const* d_in, const int* in_sizes, int n_in,
                              void* d_out, int out_size, void* d_ws, size_t ws_size,
                              hipStream_t stream) {
  const float* x      = (const float*)d_in[0];
  const float* coords = (const float*)d_in[1];
  const float* Wq = (const float*)d_in[2];
  const float* bq = (const float*)d_in[3];
  const float* Wk = (const float*)d_in[4];
  const float* bk = (const float*)d_in[5];
  const float* Wv = (const float*)d_in[6];
  const float* bv = (const float*)d_in[7];
  const float* Wo = (const float*)d_in[8];
  const float* bo = (const float*)d_in[9];

  const int S = in_sizes[1];
  const int B = in_sizes[0] / (S * DM);
  const int M = B * S;
  const float QS = 0.18033688011112042f;   // log2(e)/8

  char* w = (char*)d_ws;
  size_t off = 0;
  unsigned short* xb   = (unsigned short*)(w + off); off += (size_t)M * DM * 2;
  unsigned short* Wcat = (unsigned short*)(w + off); off += (size_t)3 * DM * DM * 2;
  unsigned short* Wob  = (unsigned short*)(w + off); off += (size_t)DM * DM * 2;
  unsigned short* QKVb = (unsigned short*)(w + off); off += (size_t)M * QLD * 2;
  unsigned short* Vtb  = (unsigned short*)(w + off); off += (size_t)M * DM * 2;
  float* tw  = (float*)(w + off); off += (size_t)S * 4;
  unsigned short* twb = (unsigned short*)(w + off); off += (size_t)S * 2;
  float* bcat = (float*)(w + off); off += (size_t)3 * DM * 4;
  unsigned short* Ob = xb;   // alias: xb dead after QKV gemm
  (void)ws_size; (void)n_in; (void)out_size;

  // fused prep (x conv, 4 weight convs, bias cat, tw) — one launch, 8 elems/thread
  {
    int nx8 = M * DM / 8, nw8 = DM * DM / 8;
    int total = nx8 + 4 * nw8;
    int tail = 3 * DM + S;
    int gridp = total / 256 + (tail + 255) / 256;
    k_prep<<<gridp, 256, 0, stream>>>(x, Wq, Wk, Wv, Wo, bq, bk, bv, coords,
                                      xb, Wcat, Wob, bcat, tw, twb, M, S, QS);
  }

  // fused QKV projection: [M,1024] x [3072,1024]^T -> [M,3072]
  // V-range blocks write Vt directly (transpose + tw + kappa) — no k_transpose kernel.
  gemm_bt<1><<<(M / BM) * (3 * DM / BN), 256, 0, stream>>>(
      xb, Wcat, bcat, QKVb, M, 3 * DM, DM, QLD, tw, Vtb, S);

  // attention
  k_attn<<<B * NHEAD * (S / 128), 256, 0, stream>>>(QKVb, Vtb, twb, Ob, S);

  // output projection (f32 out, 64x128 tile, 512 blocks)
  gemm_wo<<<(M / WBM) * (DM / BN), 256, 0, stream>>>(Ob, Wob, bo, (float*)d_out, M, DM, DM, DM);
}

// Round 20
// 106.346 us; speedup vs baseline: 1.0897x; 1.0897x over previous
//
#include <hip/hip_runtime.h>

#define DM 1024
#define NHEAD 16
#define DK 64
#define QLD 3072   // fused QKV row stride

typedef short bf16x8 __attribute__((ext_vector_type(8)));
typedef float f32x4 __attribute__((ext_vector_type(4)));

__device__ __forceinline__ unsigned short f2bf(float f) {
  union { float f; unsigned u; } v; v.f = f;
  return (unsigned short)((v.u + 0x7fffu + ((v.u >> 16) & 1u)) >> 16);
}
__device__ __forceinline__ float bf2f(unsigned short h) {
  union { unsigned u; float f; } v; v.u = ((unsigned)h) << 16; return v.f;
}
__device__ __forceinline__ float fexp2(float x) {   // bare v_exp_f32: args bounded, no fixup needed
  float r; asm("v_exp_f32 %0, %1" : "=v"(r) : "v"(x)); return r;
}

__device__ __forceinline__ void gld16(const void* g, void* l) {
  __builtin_amdgcn_global_load_lds((const __attribute__((address_space(1))) void*)g,
                                   (__attribute__((address_space(3))) void*)l, 16, 0, 0);
}

__device__ __forceinline__ uint4 pack8(float4 a, float4 b, float sc) {
  uint4 r;
  r.x = (unsigned)f2bf(a.x * sc) | ((unsigned)f2bf(a.y * sc) << 16);
  r.y = (unsigned)f2bf(a.z * sc) | ((unsigned)f2bf(a.w * sc) << 16);
  r.z = (unsigned)f2bf(b.x * sc) | ((unsigned)f2bf(b.y * sc) << 16);
  r.w = (unsigned)f2bf(b.z * sc) | ((unsigned)f2bf(b.w * sc) << 16);
  return r;
}

// kappa: key = K(slot) within each 64-tile; bijective. Matches swapped-QK register layout.
__device__ __forceinline__ int kappa(int p) {
  return (p & 32) + (((p & 7) >> 2) << 4) + (((p >> 3) & 3) << 2) + (p & 3);
}

// ---------------- fused prep: x conv + 4 weight convs (8 elems/thread) + bias cat + tw ----------------
__global__ void k_prep(const float* __restrict__ x, const float* __restrict__ Wq,
                       const float* __restrict__ Wk, const float* __restrict__ Wv,
                       const float* __restrict__ Wo, const float* __restrict__ bq,
                       const float* __restrict__ bk, const float* __restrict__ bv,
                       const float* __restrict__ coords,
                       unsigned short* __restrict__ xb, unsigned short* __restrict__ Wcat,
                       unsigned short* __restrict__ Wob, float* __restrict__ bcat,
                       float* __restrict__ tw, unsigned short* __restrict__ twb,
                       int M, int S, float QS) {
  const int nx8 = M * DM / 8;      // x 8-float chunks
  const int nw8 = DM * DM / 8;     // per-weight 8-float chunks
  const int total = nx8 + 4 * nw8;
  int gid = blockIdx.x * 256 + threadIdx.x;

  auto conv8 = [&](const float* src, unsigned short* dst, int idx, float sc) {
    float4 a = *(const float4*)(src + idx * 8);
    float4 b = *(const float4*)(src + idx * 8 + 4);
    *(uint4*)(dst + idx * 8) = pack8(a, b, sc);
  };

  if (gid < nx8) { conv8(x, xb, gid, 1.0f); return; }
  if (gid < nx8 + nw8) { conv8(Wq, Wcat, gid - nx8, QS); return; }
  if (gid < nx8 + 2 * nw8) { conv8(Wk, Wcat + DM * DM, gid - nx8 - nw8, 1.0f); return; }
  if (gid < nx8 + 3 * nw8) { conv8(Wv, Wcat + 2 * DM * DM, gid - nx8 - 2 * nw8, 1.0f); return; }
  if (gid < total) { conv8(Wo, Wob, gid - nx8 - 3 * nw8, 1.0f); return; }

  int r = gid - total;
  if (r < 3 * DM) {
    float v = (r < DM) ? bq[r] * QS : (r < 2 * DM ? bk[r - DM] : bv[r - 2 * DM]);
    bcat[r] = v;
    return;
  }
  r -= 3 * DM;
  if (r < S) {
    auto twval = [&](int k) {
      float a = (k > 0)     ? fabsf(coords[k] - coords[k - 1]) : 0.f;
      float b = (k < S - 1) ? fabsf(coords[k + 1] - coords[k]) : 0.f;
      return 0.5f * (a + b);
    };
    tw[r] = twval(r);
    int key = (r & ~63) + kappa(r & 63);
    twb[r] = f2bf(twval(key));
  }
}

// ---------------- GEMM: C[M,N] = A[M,K] * B[N,K]^T + bias (bf16 out) ----------------
// T2 XOR-swizzled LDS; C stored via LDS restage for coalescing.
// VFUSE: blocks covering the V feature range write transposed/tw-scaled/kappa-permuted
// Vt tiles directly (and skip the C store) — replaces the k_transpose kernel.
#define BM 128
#define BN 128
#define BKK 64

template<int VFUSE>
__global__ __launch_bounds__(256)
void gemm_bt(const unsigned short* __restrict__ A, const unsigned short* __restrict__ B,
             const float* __restrict__ bias, void* __restrict__ C,
             int M, int N, int K, int ldc,
             const float* __restrict__ twp, unsigned short* __restrict__ Vt, int S) {
  __shared__ __align__(16) unsigned short smem[4][BM * BKK];   // [0..1]=A dbuf, [2..3]=B dbuf
  const int tid = threadIdx.x;
  const int lane = tid & 63;
  const int wid = tid >> 6;
  const int rr = lane & 15, g = lane >> 4;
  const int nbn = N / BN;
  const int cpx = gridDim.x >> 3;
  const int bid = ((gridDim.x & 7) == 0) ? (blockIdx.x & 7) * cpx + (blockIdx.x >> 3)
                                         : blockIdx.x;
  const int bm = bid / nbn, bn = bid % nbn;
  const int wr = wid >> 1, wc = wid & 1;
  const int nkt = K / BKK;

  const unsigned short* Abase = A + (size_t)bm * BM * K;
  const unsigned short* Bbase = B + (size_t)bn * BN * K;

  auto stage = [&](int buf, int kt) {
#pragma unroll
    for (int j = 0; j < 4; ++j) {
      int o = j * 256 + tid;
      int row = o >> 3;
      int cb = ((o & 7) * 16) ^ ((row & 7) << 4);   // inverse-swizzled source byte col
      gld16((const char*)(Abase + (size_t)row * K + kt * BKK) + cb, &smem[buf][o * 8]);
      gld16((const char*)(Bbase + (size_t)row * K + kt * BKK) + cb, &smem[2 + buf][o * 8]);
    }
  };

  f32x4 acc[4][4] = {};
  stage(0, 0);
  int cur = 0;
  const int sw = (rr & 7) << 4;
  for (int kt = 0; kt < nkt; ++kt) {
    __syncthreads();
    if (kt + 1 < nkt) stage(cur ^ 1, kt + 1);
    const char* a0 = (const char*)&smem[cur][0];
    const char* b0 = (const char*)&smem[2 + cur][0];
#pragma unroll
    for (int kk = 0; kk < 2; ++kk) {
      const int co = (kk * 64 + g * 16);
      bf16x8 af[4], bfr[4];
#pragma unroll
      for (int m = 0; m < 4; ++m)
        af[m] = *(const bf16x8*)(a0 + (wr * 64 + m * 16 + rr) * 128 + (co ^ sw));
#pragma unroll
      for (int n = 0; n < 4; ++n)
        bfr[n] = *(const bf16x8*)(b0 + (wc * 64 + n * 16 + rr) * 128 + (co ^ sw));
      __builtin_amdgcn_s_setprio(1);
#pragma unroll
      for (int m = 0; m < 4; ++m)
#pragma unroll
        for (int n = 0; n < 4; ++n)
          acc[m][n] = __builtin_amdgcn_mfma_f32_16x16x32_bf16(af[m], bfr[n], acc[m][n], 0, 0, 0);
      __builtin_amdgcn_s_setprio(0);
    }
    cur ^= 1;
  }

  const int ccol0 = bn * BN + wc * 64;
  // restage through LDS (row pad 136 shorts)
  unsigned short* L = &smem[0][0];   // 128*136 = 17408 shorts <= 32768
  __syncthreads();                   // all fragment reads of smem done
#pragma unroll
  for (int n = 0; n < 4; ++n) {
    const float bn_ = bias ? bias[ccol0 + n * 16 + rr] : 0.f;
#pragma unroll
    for (int m = 0; m < 4; ++m)
#pragma unroll
      for (int r = 0; r < 4; ++r)
        L[(wr * 64 + m * 16 + g * 4 + r) * 136 + wc * 64 + n * 16 + rr] =
            f2bf(acc[m][n][r] + bn_);
  }
  __syncthreads();
  if (VFUSE && bn >= (2 * DM) / BN) {
    // ---- fused V-transpose epilogue: Vt[bh][d][s] with tw prescale + kappa permute ----
    const int tilesPerB = S / BM;
    const int bb = bm / tilesPerB;
    const int s0 = (bm % tilesPerB) * BM;
    const int vcol0 = bn * BN - 2 * DM;        // first V feature col of this tile
    const int hh = tid >> 7;                   // head-half within tile (0/1)
    const int dd = (tid >> 1) & 63;            // d within head
    const int stl = tid & 1;                   // which 64-s subtile
    const int head = (vcol0 >> 6) + hh;
    const int lcol = hh * 64 + dd;
    unsigned short* vdst = Vt + ((size_t)(bb * NHEAD + head) * DK + dd) * S + s0 + stl * 64;
    const float* twg = twp + s0 + stl * 64;
    unsigned short tmp[8];
#pragma unroll
    for (int j8 = 0; j8 < 8; ++j8) {
#pragma unroll
      for (int j = 0; j < 8; ++j) {
        const int kl = kappa(j8 * 8 + j);
        tmp[j] = f2bf(bf2f(L[(stl * 64 + kl) * 136 + lcol]) * twg[kl]);
      }
      *(uint4*)&vdst[j8 * 8] = *(const uint4*)&tmp[0];
    }
  } else {
    unsigned short* Cb = (unsigned short*)C + (size_t)(bm * BM) * ldc + bn * BN;
#pragma unroll
    for (int i = 0; i < 8; ++i) {
      int o = i * 256 + tid;
      int row = o >> 4;
      int cc = (o & 15) * 8;
      uint4 v = *(const uint4*)&L[row * 136 + cc];
      *(uint4*)&Cb[(size_t)row * ldc + cc] = v;
    }
  }
}

// ---------------- Wo GEMM: C[M,N] f32 = A[M,K]*B[N,K]^T + bias; BM=64 x BN=128 tile ----------------
// 512 blocks (2/CU). 2x2 wave grid, per-wave 32x64. f32 LDS-restaged coalesced store.
#define WBM 64
__global__ __launch_bounds__(256)
void gemm_wo(const unsigned short* __restrict__ A, const unsigned short* __restrict__ B,
             const float* __restrict__ bias, float* __restrict__ C,
             int M, int N, int K, int ldc) {
  __shared__ __align__(16) unsigned short smem[6][WBM * BKK];  // [0..1]=A dbuf(16KB), [2..5]=B dbuf(32KB)
  const int tid = threadIdx.x;
  const int lane = tid & 63;
  const int wid = tid >> 6;
  const int rr = lane & 15, g = lane >> 4;
  const int nbn = N / BN;                       // 8
  const int cpx = gridDim.x >> 3;
  const int bid = (blockIdx.x & 7) * cpx + (blockIdx.x >> 3);   // grid 512 % 8 == 0
  const int bm = bid / nbn, bn = bid % nbn;
  const int wr = wid >> 1, wc = wid & 1;
  const int nkt = K / BKK;

  const unsigned short* Abase = A + (size_t)bm * WBM * K;
  const unsigned short* Bbase = B + (size_t)bn * BN * K;

  auto stage = [&](int buf, int kt) {
    {   // A: 64 rows x 128B = 512 chunks -> 2/thread
#pragma unroll
      for (int j = 0; j < 2; ++j) {
        int o = j * 256 + tid;
        int row = o >> 3;
        int cb = ((o & 7) * 16) ^ ((row & 7) << 4);
        gld16((const char*)(Abase + (size_t)row * K + kt * BKK) + cb, &smem[buf][o * 8]);
      }
    }
    {   // B: 128 rows x 128B = 1024 chunks -> 4/thread
#pragma unroll
      for (int j = 0; j < 4; ++j) {
        int o = j * 256 + tid;
        int row = o >> 3;
        int cb = ((o & 7) * 16) ^ ((row & 7) << 4);
        gld16((const char*)(Bbase + (size_t)row * K + kt * BKK) + cb, &smem[2 + buf * 2][o * 8]);
      }
    }
  };

  f32x4 acc[2][4] = {};
  stage(0, 0);
  int cur = 0;
  const int sw = (rr & 7) << 4;
  for (int kt = 0; kt < nkt; ++kt) {
    __syncthreads();
    if (kt + 1 < nkt) stage(cur ^ 1, kt + 1);
    const char* a0 = (const char*)&smem[cur][0];
    const char* b0 = (const char*)&smem[2 + cur * 2][0];
#pragma unroll
    for (int kk = 0; kk < 2; ++kk) {
      const int co = (kk * 64 + g * 16);
      bf16x8 af[2], bfr[4];
#pragma unroll
      for (int m = 0; m < 2; ++m)
        af[m] = *(const bf16x8*)(a0 + (wr * 32 + m * 16 + rr) * 128 + (co ^ sw));
#pragma unroll
      for (int n = 0; n < 4; ++n)
        bfr[n] = *(const bf16x8*)(b0 + (wc * 64 + n * 16 + rr) * 128 + (co ^ sw));
      __builtin_amdgcn_s_setprio(1);
#pragma unroll
      for (int m = 0; m < 2; ++m)
#pragma unroll
        for (int n = 0; n < 4; ++n)
          acc[m][n] = __builtin_amdgcn_mfma_f32_16x16x32_bf16(af[m], bfr[n], acc[m][n], 0, 0, 0);
      __builtin_amdgcn_s_setprio(0);
    }
    cur ^= 1;
  }

  // f32 restage: 64 rows x 132 f32 (pad 4 -> banks shift 4/row), 33.8KB within 48KB smem
  float* Lf = (float*)&smem[0][0];
  __syncthreads();
#pragma unroll
  for (int n = 0; n < 4; ++n) {
    const float bn_ = bias[bn * BN + wc * 64 + n * 16 + rr];
#pragma unroll
    for (int m = 0; m < 2; ++m)
#pragma unroll
      for (int r = 0; r < 4; ++r)
        Lf[(wr * 32 + m * 16 + g * 4 + r) * 132 + wc * 64 + n * 16 + rr] =
            acc[m][n][r] + bn_;
  }
  __syncthreads();
  float* Cb = C + (size_t)(bm * WBM) * ldc + bn * BN;
#pragma unroll
  for (int i = 0; i < 8; ++i) {
    int o = i * 256 + tid;         // 2048 uint4 chunks: 64 rows x 32 chunks
    int row = o >> 5;
    int cc = (o & 31) * 4;
    float4 v = *(const float4*)&Lf[row * 132 + cc];
    *(float4*)&Cb[(size_t)row * ldc + cc] = v;
  }
}

// ---------------- attention: swapped QK^T, P in registers, KVBLK=128 ----------------
// 4 waves x 32 q-rows = 128 q-rows per block; 128-key staged tiles, two 64-key halves.
// sV split per-half (128B rows) -> conflict-free V reads; coalesced epilogue via LDS restage.
__global__ __launch_bounds__(256)
void k_attn(const unsigned short* __restrict__ QKV, const unsigned short* __restrict__ Vt,
            const unsigned short* __restrict__ twb, unsigned short* __restrict__ O, int S) {
  __shared__ __align__(16) unsigned short sK[2][128 * 64];      // 128 keys x 64 d
  __shared__ __align__(16) unsigned short sV[2][2][64 * 64];    // [buf][half][64 d][64 slots]
  const int tid = threadIdx.x, lane = tid & 63, wid = tid >> 6;
  const int rr = lane & 15, g = lane >> 4;
  const int nqt = S / 128;
  const int cpx = gridDim.x >> 3;
  const int swz = (blockIdx.x & 7) * cpx + (blockIdx.x >> 3);
  const int qt = swz % nqt;
  const int bh = swz / nqt;
  const int h = bh & (NHEAD - 1), b = bh / NHEAD;

  const unsigned short* Qbase = QKV + ((size_t)b * S + qt * 128 + wid * 32) * QLD + h * DK;
  const unsigned short* Kbase = QKV + (size_t)b * S * QLD + DM + h * DK;
  const unsigned short* Vbase = Vt + (size_t)bh * DK * S;

  bf16x8 aq[2][2];
#pragma unroll
  for (int qm = 0; qm < 2; ++qm) {
    aq[qm][0] = *(const bf16x8*)&Qbase[(size_t)(qm * 16 + rr) * QLD + g * 8];
    aq[qm][1] = *(const bf16x8*)&Qbase[(size_t)(qm * 16 + rr) * QLD + 32 + g * 8];
  }

  f32x4 acc[2][5] = {};
  const f32x4 z0 = {};

  auto stage = [&](int buf, int kt) {
    // K: 128 rows x 128B, 1024 chunks
#pragma unroll
    for (int j = 0; j < 4; ++j) {
      int o = j * 256 + tid;
      int row = o >> 3;
      int cb = ((o & 7) * 16) ^ ((row & 7) << 4);
      gld16((const char*)(Kbase + (size_t)(kt * 128 + row) * QLD) + cb, &sK[buf][o * 8]);
    }
    // V: 2 halves x (64 rows x 128B), 1024 chunks; dest stays linear (o*8)
#pragma unroll
    for (int j = 0; j < 4; ++j) {
      int o = j * 256 + tid;
      int half_ = o >> 9;
      int r = o & 511;
      int row = r >> 3;
      int cb = ((r & 7) * 16) ^ ((row & 7) << 4);
      gld16((const char*)(Vbase + (size_t)row * S + kt * 128 + half_ * 64) + cb,
            &sV[buf][0][o * 8]);
    }
  };

  stage(0, 0);
  int cur = 0;
  const int nkt = S / 128;
  const int swr = (rr & 7) << 4;   // row&7 == rr&7 for all frag rows
  for (int kt = 0; kt < nkt; ++kt) {
    __syncthreads();
    if (kt + 1 < nkt) stage(cur ^ 1, kt + 1);

#pragma unroll
    for (int half = 0; half < 2; ++half) {
      // ---- hoisted loads: K frags, V frags, tw frags all issued up front ----
      bf16x8 kA[4][2];
#pragma unroll
      for (int f = 0; f < 4; ++f) {
        const int row = half * 64 + f * 16 + rr;
        kA[f][0] = *(const bf16x8*)((const char*)&sK[cur][row * 64] + ((g * 16) ^ swr));
        kA[f][1] = *(const bf16x8*)((const char*)&sK[cur][row * 64] + ((64 + g * 16) ^ swr));
      }
      bf16x8 vB[2][4];
#pragma unroll
      for (int kk = 0; kk < 2; ++kk)
#pragma unroll
        for (int n = 0; n < 4; ++n) {
          const int vrow = n * 16 + rr;
          const int cb = (kk * 64 + g * 16) ^ ((vrow & 7) << 4);
          vB[kk][n] = *(const bf16x8*)((const char*)&sV[cur][half][vrow * 64] + cb);
        }
      bf16x8 tw0 = *(const bf16x8*)&twb[kt * 128 + half * 64 + g * 8];
      bf16x8 tw1 = *(const bf16x8*)&twb[kt * 128 + half * 64 + 32 + g * 8];

      // ---- swapped scores: s[qm][f] = P[key=16f+4g+r][q=qm*16+rr] ----
      f32x4 s[2][4];
      __builtin_amdgcn_s_setprio(1);
#pragma unroll
      for (int f = 0; f < 4; ++f)
#pragma unroll
        for (int qm = 0; qm < 2; ++qm) {
          f32x4 z = __builtin_amdgcn_mfma_f32_16x16x32_bf16(kA[f][0], aq[qm][0], z0, 0, 0, 0);
          s[qm][f] = __builtin_amdgcn_mfma_f32_16x16x32_bf16(kA[f][1], aq[qm][1], z, 0, 0, 0);
        }
      __builtin_amdgcn_s_setprio(0);

      // ---- p = exp2(s) in place (lane-local) ----
#pragma unroll
      for (int qm = 0; qm < 2; ++qm)
#pragma unroll
        for (int f = 0; f < 4; ++f)
#pragma unroll
          for (int r = 0; r < 4; ++r)
            s[qm][f][r] = fexp2(s[qm][f][r]);

      // ---- pack P into A-frags: slot kk*32+g*8+j -> (f=2kk+(j>>2), r=j&3) ----
      bf16x8 pa[2][2];
#pragma unroll
      for (int qm = 0; qm < 2; ++qm)
#pragma unroll
        for (int kk = 0; kk < 2; ++kk) {
          union { bf16x8 v; unsigned u[4]; } pk;
          asm("v_cvt_pk_bf16_f32 %0, %1, %2" : "=v"(pk.u[0]) : "v"(s[qm][2*kk][0]),   "v"(s[qm][2*kk][1]));
          asm("v_cvt_pk_bf16_f32 %0, %1, %2" : "=v"(pk.u[1]) : "v"(s[qm][2*kk][2]),   "v"(s[qm][2*kk][3]));
          asm("v_cvt_pk_bf16_f32 %0, %1, %2" : "=v"(pk.u[2]) : "v"(s[qm][2*kk+1][0]), "v"(s[qm][2*kk+1][1]));
          asm("v_cvt_pk_bf16_f32 %0, %1, %2" : "=v"(pk.u[3]) : "v"(s[qm][2*kk+1][2]), "v"(s[qm][2*kk+1][3]));
          pa[qm][kk] = pk.v;
        }

      // ---- PV + denominator (V frags already in registers) ----
      __builtin_amdgcn_s_setprio(1);
#pragma unroll
      for (int kk = 0; kk < 2; ++kk) {
#pragma unroll
        for (int n = 0; n < 4; ++n)
#pragma unroll
          for (int qm = 0; qm < 2; ++qm)
            acc[qm][n] = __builtin_amdgcn_mfma_f32_16x16x32_bf16(pa[qm][kk], vB[kk][n], acc[qm][n], 0, 0, 0);
#pragma unroll
        for (int qm = 0; qm < 2; ++qm)
          acc[qm][4] = __builtin_amdgcn_mfma_f32_16x16x32_bf16(pa[qm][kk], kk ? tw1 : tw0, acc[qm][4], 0, 0, 0);
      }
      __builtin_amdgcn_s_setprio(0);
    }
    cur ^= 1;
  }

  // ---- coalesced epilogue: restage O tile (128 x 64 bf16) in LDS, 16B/lane stores ----
  unsigned short* L = &sK[0][0];   // 128*72 = 9216 shorts <= 16384 (sK region)
  __syncthreads();                 // all waves done reading sK/sV
#pragma unroll
  for (int qm = 0; qm < 2; ++qm)
#pragma unroll
    for (int n = 0; n < 4; ++n)
#pragma unroll
      for (int r = 0; r < 4; ++r)
        L[(wid * 32 + qm * 16 + g * 4 + r) * 72 + n * 16 + rr] =
            f2bf(acc[qm][n][r] / acc[qm][4][r]);
  __syncthreads();
  unsigned short* Ob = O + ((size_t)b * S + qt * 128) * DM + h * DK;
#pragma unroll
  for (int i = 0; i < 4; ++i) {
    int o = i * 256 + tid;         // 1024 chunks: 128 rows x 8 chunks of 16B
    int row = o >> 3;
    int c = (o & 7) * 8;
    uint4 v = *(const uint4*)&L[row * 72 + c];
    *(uint4*)&Ob[(size_t)row * DM + c] = v;
  }
}

// ---------------- launch ----------------
extern "C" void kernel_launch(void* const* d_in, const int* in_sizes, int n_in,
                              void* d_out, int out_size, void* d_ws, size_t ws_size,
                              hipStream_t stream) {
  const float* x      = (const float*)d_in[0];
  const float* coords = (const float*)d_in[1];
  const float* Wq = (const float*)d_in[2];
  const float* bq = (const float*)d_in[3];
  const float* Wk = (const float*)d_in[4];
  const float* bk = (const float*)d_in[5];
  const float* Wv = (const float*)d_in[6];
  const float* bv = (const float*)d_in[7];
  const float* Wo = (const float*)d_in[8];
  const float* bo = (const float*)d_in[9];

  const int S = in_sizes[1];
  const int B = in_sizes[0] / (S * DM);
  const int M = B * S;
  const float QS = 0.18033688011112042f;   // log2(e)/8

  char* w = (char*)d_ws;
  size_t off = 0;
  unsigned short* xb   = (unsigned short*)(w + off); off += (size_t)M * DM * 2;
  unsigned short* Wcat = (unsigned short*)(w + off); off += (size_t)3 * DM * DM * 2;
  unsigned short* Wob  = (unsigned short*)(w + off); off += (size_t)DM * DM * 2;
  unsigned short* QKVb = (unsigned short*)(w + off); off += (size_t)M * QLD * 2;
  unsigned short* Vtb  = (unsigned short*)(w + off); off += (size_t)M * DM * 2;
  float* tw  = (float*)(w + off); off += (size_t)S * 4;
  unsigned short* twb = (unsigned short*)(w + off); off += (size_t)S * 2;
  float* bcat = (float*)(w + off); off += (size_t)3 * DM * 4;
  unsigned short* Ob = xb;   // alias: xb dead after QKV gemm
  (void)ws_size; (void)n_in; (void)out_size;

  // fused prep (x conv, 4 weight convs, bias cat, tw) — one launch, 8 elems/thread
  {
    int nx8 = M * DM / 8, nw8 = DM * DM / 8;
    int total = nx8 + 4 * nw8;
    int tail = 3 * DM + S;
    int gridp = total / 256 + (tail + 255) / 256;
    k_prep<<<gridp, 256, 0, stream>>>(x, Wq, Wk, Wv, Wo, bq, bk, bv, coords,
                                      xb, Wcat, Wob, bcat, tw, twb, M, S, QS);
  }

  // fused QKV projection: [M,1024] x [3072,1024]^T -> [M,3072]
  // V-range blocks write Vt directly (transpose + tw + kappa) — no k_transpose kernel.
  gemm_bt<1><<<(M / BM) * (3 * DM / BN), 256, 0, stream>>>(
      xb, Wcat, bcat, QKVb, M, 3 * DM, DM, QLD, tw, Vtb, S);

  // attention
  k_attn<<<B * NHEAD * (S / 128), 256, 0, stream>>>(QKVb, Vtb, twb, Ob, S);

  // output projection (f32 out, 64x128 tile, 512 blocks)
  gemm_wo<<<(M / WBM) * (DM / BN), 256, 0, stream>>>(Ob, Wob, bo, (float*)d_out, M, DM, DM, DM);
}